// Round 12
// baseline (42.023 us; speedup 1.0000x reference)
//
#include <hip/hip_runtime.h>
#include <hip/hip_bf16.h>

#define NW 12
#define DIM 4096
#define NL 4
#define NGATE 48
#define NOUT 4
#define TPB 512           // 2 samples x 256 threads

typedef float f32x2 __attribute__((ext_vector_type(2)));
typedef float f32x4 __attribute__((ext_vector_type(4)));
typedef unsigned u32x4 __attribute__((ext_vector_type(4)));
typedef short short8 __attribute__((ext_vector_type(8)));

// ======================= shared constexpr GF(2) machinery =======================
constexpr int pcnt(unsigned x){ return __builtin_popcount(x); }
constexpr int msbp(unsigned x){ return x ? 31-__builtin_clz(x) : -1; }
constexpr unsigned ring_fwd(unsigned x,int r){
  for(int w=0;w<NW;++w){ int c=NW-1-w,t=NW-1-((w+r)%NW); x^=((x>>c)&1u)<<t; } return x;
}
constexpr unsigned ring_rev(unsigned x,int r){
  for(int w=NW-1;w>=0;--w){ int c=NW-1-w,t=NW-1-((w+r)%NW); x^=((x>>c)&1u)<<t; } return x;
}
struct Mat { unsigned col[12]; };
constexpr unsigned apply_cols(const Mat&M, unsigned v){
  unsigned r=0; for(int j=0;j<12;++j) if((v>>j)&1u) r^=M.col[j]; return r;
}
constexpr unsigned apply_rows(const unsigned* rows, unsigned v){
  unsigned r=0; for(int i=0;i<12;++i) r|=(unsigned)(pcnt(rows[i]&v)&1)<<i; return r;
}
constexpr bool invert_rows(const Mat&M, unsigned* ri_out){
  unsigned rb[12]={}, ri[12]={};
  for(int i=0;i<12;++i){ unsigned r=0; for(int j=0;j<12;++j) r|=((M.col[j]>>i)&1u)<<j; rb[i]=r; ri[i]=1u<<i; }
  for(int c=0;c<12;++c){
    int piv=-1; for(int r=c;r<12;++r) if((rb[r]>>c)&1u){piv=r;break;}
    if(piv<0) return false;
    unsigned t=rb[c]; rb[c]=rb[piv]; rb[piv]=t; t=ri[c]; ri[c]=ri[piv]; ri[piv]=t;
    for(int r=0;r<12;++r) if(r!=c&&((rb[r]>>c)&1u)){ rb[r]^=rb[c]; ri[r]^=ri[c]; }
  }
  for(int i=0;i<12;++i) ri_out[i]=ri[i];
  return true;
}
constexpr int nullspace4(const unsigned* A0, unsigned* out){
  unsigned A[4]={}; for(int i=0;i<4;++i) A[i]=A0[i];
  int rank=0; int pivc[4]={-1,-1,-1,-1};
  for(int c=0;c<12&&rank<4;++c){
    int piv=-1; for(int r=rank;r<4;++r) if((A[r]>>c)&1u){piv=r;break;}
    if(piv<0) continue;
    unsigned t=A[rank];A[rank]=A[piv];A[piv]=t;
    for(int r=0;r<4;++r) if(r!=rank&&((A[r]>>c)&1u)) A[r]^=A[rank];
    pivc[rank]=c; ++rank;
  }
  if(rank!=4) return -1;
  bool ispiv[12]={};
  for(int r=0;r<4;++r) ispiv[pivc[r]]=true;
  int cnt=0;
  for(int f=0;f<12;++f) if(!ispiv[f]){
    unsigned v=1u<<f;
    for(int r=0;r<4;++r) if((A[r]>>f)&1u) v|=1u<<pivc[r];
    out[cnt++]=v;
  }
  return cnt;
}
struct Ech { unsigned r[12]; int lead[12]; int n; };
constexpr unsigned ech_red(const Ech&e, unsigned v){
  int mv=msbp(v);
  for(int i=0;i<e.n&&v;++i) if(e.lead[i]==mv){ v^=e.r[i]; mv=msbp(v); }
  return v;
}
constexpr void ech_add(Ech&e, unsigned v){
  int l=msbp(v); int pos=e.n;
  while(pos>0&&e.lead[pos-1]<l){ e.r[pos]=e.r[pos-1]; e.lead[pos]=e.lead[pos-1]; --pos; }
  e.r[pos]=v; e.lead[pos]=l; e.n+=1;
}

struct Circ {
  unsigned M[NL][12]; unsigned RM[NL][12]; unsigned MR[NOUT];
};
constexpr Circ make_circ(){
  Circ C{};
  unsigned cols[12]={}, icols[12]={};
  for(int p=0;p<12;++p){ cols[p]=1u<<p; icols[p]=1u<<p; }
  for(int l=0;l<NL;++l){
    for(int w=0;w<NW;++w){
      int p=NW-1-w;
      C.M[l][w]=icols[p];
      unsigned r=0; for(int j=0;j<12;++j) r|=((cols[j]>>p)&1u)<<j;
      C.RM[l][w]=r;
    }
    int rr=(l%(NW-1))+1;
    for(int j=0;j<12;++j) cols[j]=ring_fwd(cols[j],rr);
    unsigned nic[12]={};
    for(int p=0;p<12;++p){
      unsigned y=ring_rev(1u<<p,rr), v=0;
      for(int q=0;q<12;++q) if((y>>q)&1u) v^=icols[q];
      nic[p]=v;
    }
    for(int p=0;p<12;++p) icols[p]=nic[p];
  }
  for(int o=0;o<NOUT;++o){
    int p=NW-1-o; unsigned r=0;
    for(int j=0;j<12;++j) r|=((cols[j]>>p)&1u)<<j;
    C.MR[o]=r;
  }
  return C;
}

// ======================= Plan2: MFMA layout (R9-proven) =======================
constexpr unsigned amap(unsigned v){ return (v>>8)*2048u + (v&255u)*8u; }

struct Plan2 {
  unsigned SCOLt[8];
  unsigned SK16[16];
  unsigned TM;
  unsigned WBC[12][8], WOFF[12][16];
  unsigned RBC[12][8], ROFF[12][16];
  unsigned SRt[NOUT], KP[NOUT];
  bool ok;
};

constexpr Plan2 make_plan2(){
  Plan2 P{}; P.ok=true;
  constexpr Circ C = make_circ();
  const int SIGl[8] = {0,1,2,3,10,11,6,7};
  Mat Bprev{}; for(int j=0;j<12;++j) Bprev.col[j]=1u<<j;
  for(int g=0; g<12; ++g){
    int l=g/3, j0=(g%3)*4;
    unsigned mi[4]={}, rmi[4]={};
    for(int i=0;i<4;++i){ mi[i]=C.M[l][j0+i]; rmi[i]=C.RM[l][j0+i]; }
    unsigned u[8]={};
    if(nullspace4(rmi,u)!=8){ P.ok=false; return P; }
    unsigned binv[12]={};
    if(!invert_rows(Bprev,binv)){ P.ok=false; return P; }
    for(int s=0;s<8;++s) u[s]=apply_rows(binv,u[s]);
    Mat Bg{};
    for(int j=0;j<8;++j) Bg.col[j]=apply_cols(Bprev,u[j]);
    for(int i=0;i<4;++i) Bg.col[8+i]=mi[i];
    unsigned tinv[12]={};
    if(!invert_rows(Bg,tinv)){ P.ok=false; return P; }
    for(int i=0;i<4;++i)
      for(int j=0;j<12;++j){
        int want=(j==8+i)?1:0;
        if((pcnt(Bg.col[j]&rmi[i])&1)!=want){ P.ok=false; return P; }
      }
    if(g==0){
      for(int j=0;j<8;++j) P.SCOLt[j]=Bg.col[SIGl[j]];
      for(int idx=0;idx<16;++idx){
        unsigned v=0;
        if((idx>>2)&1) v^=Bg.col[4];
        if((idx>>2)&2) v^=Bg.col[5];
        if(idx&1) v^=Bg.col[8];
        if(idx&2) v^=Bg.col[9];
        P.SK16[idx]=v; P.TM|=v;
      }
    } else {
      unsigned rk[4]={};
      for(int i=0;i<4;++i){
        rk[i]=apply_rows(binv,mi[i]);
        if(apply_cols(Bprev,rk[i])!=mi[i]){ P.ok=false; return P; }
      }
      unsigned s2b[6]={u[0],u[1],u[2],u[3],rk[2],rk[3]};
      unsigned rows[12]={}; int nr=0;
      Ech P1{},P2{},ER{};
      for(int pick=0;pick<4;++pick){
        unsigned fx=0, fy=0;
        const int b1s[6]={0,1,2,3,10,11};
        for(int ii=0;ii<6;++ii){
          unsigned f=1u<<b1s[ii];
          unsigned p1=(f&15u)|(((f>>10)&3u)<<4);
          if(ech_red(P1,p1)){ fx=f; break; }
        }
        for(int bb=0;bb<12;++bb){
          unsigned f=1u<<bb, p2=0;
          for(int i2=0;i2<6;++i2) p2|=(unsigned)(pcnt(f&s2b[i2])&1)<<i2;
          if(ech_red(P2,p2)){ fy=f; break; }
        }
        if(!fx||!fy){ P.ok=false; return P; }
        unsigned cand[3]={fx,fy,fx^fy};
        unsigned chosen=0, cp1=0, cp2=0;
        for(int ci=0; ci<3 && !chosen; ++ci){
          unsigned f=cand[ci];
          unsigned p1=(f&15u)|(((f>>10)&3u)<<4);
          unsigned p2=0; for(int i2=0;i2<6;++i2) p2|=(unsigned)(pcnt(f&s2b[i2])&1)<<i2;
          if(ech_red(P1,p1)&&ech_red(P2,p2)){ chosen=f; cp1=p1; cp2=p2; }
        }
        if(!chosen){ P.ok=false; return P; }
        { unsigned v1=ech_red(P1,cp1); ech_add(P1,v1); }
        { unsigned v2=ech_red(P2,cp2); ech_add(P2,v2); }
        { unsigned vr=ech_red(ER,chosen); if(!vr){ P.ok=false; return P; } ech_add(ER,vr); }
        rows[nr++]=chosen;
      }
      for(int bb=0;bb<12 && nr<12;++bb){
        unsigned vr=ech_red(ER,1u<<bb); if(!vr) continue;
        ech_add(ER,vr); rows[nr++]=1u<<bb;
      }
      if(nr!=12){ P.ok=false; return P; }
      unsigned PhiCol[12]={};
      for(int j=0;j<12;++j){
        unsigned v=0;
        for(int i=0;i<12;++i) v|=(unsigned)((rows[i]>>j)&1u)<<i;
        PhiCol[j]=v;
      }
      unsigned PhiM[12]={};
      for(int j=0;j<12;++j){
        unsigned src=(j<8)? u[j] : rk[j-8];
        unsigned v=0;
        for(int q2=0;q2<12;++q2) if((src>>q2)&1u) v^=PhiCol[q2];
        PhiM[j]=v;
      }
      for(int j=0;j<8;++j){
        P.WBC[g][j]=amap(PhiCol[SIGl[j]]);
        P.RBC[g][j]=amap(PhiM[SIGl[j]]);
      }
      for(int idx=0;idx<16;++idx){
        unsigned wv=0, rv=0;
        if((idx>>2)&1){ wv^=PhiCol[4]; rv^=PhiM[4]; }
        if((idx>>2)&2){ wv^=PhiCol[5]; rv^=PhiM[5]; }
        if(idx&1){ wv^=PhiCol[8]; rv^=PhiM[8]; }
        if(idx&2){ wv^=PhiCol[9]; rv^=PhiM[9]; }
        P.WOFF[g][idx]=amap(wv); P.ROFF[g][idx]=amap(rv);
      }
    }
    Bprev=Bg;
  }
  for(int o=0;o<NOUT;++o){
    unsigned sr=0;
    for(int j=0;j<12;++j) sr|=(unsigned)(pcnt(Bprev.col[j]&C.MR[o])&1)<<j;
    unsigned srt=0;
    const int SIGl2[8] = {0,1,2,3,10,11,6,7};
    for(int j=0;j<8;++j) srt|=((sr>>SIGl2[j])&1u)<<j;
    P.SRt[o]=srt;
    unsigned kp=0;
    for(int idx=0;idx<16;++idx){
      int T=idx>>2, q=idx&3;
      unsigned bit=(((sr>>4)&1u)&(unsigned)(T&1))^(((sr>>5)&1u)&(unsigned)((T>>1)&1))
                  ^(((sr>>8)&1u)&(unsigned)(q&1))^(((sr>>9)&1u)&(unsigned)((q>>1)&1));
      kp|=bit<<idx;
    }
    P.KP[o]=kp;
  }
  return P;
}

constexpr Plan2 PL2C = make_plan2();
static_assert(PL2C.ok, "plan2 failed");
__device__ constexpr Plan2 PL2 = PL2C;

// ======================= device helpers =======================
__device__ __forceinline__ void gate_coeffs(const float* __restrict__ wts, int gi, float* o){
  const float* w = wts + gi*3;
  float st,ct;  sincosf(0.5f*w[1],&st,&ct);
  float sap,cap; sincosf(0.5f*(w[0]+w[2]),&sap,&cap);
  float sam,cam; sincosf(0.5f*(w[0]-w[2]),&sam,&cam);
  o[0]= cap*ct; o[1]=-sap*ct;
  o[2]=-cam*st; o[3]=-sam*st;
  o[4]= cam*st; o[5]=-sam*st;
  o[6]= cap*ct; o[7]= sap*ct;
}
__device__ __forceinline__ unsigned cvtpk(float a, float b){
  unsigned r; asm("v_cvt_pk_bf16_f32 %0, %1, %2" : "=v"(r) : "v"(a), "v"(b)); return r;
}
__device__ __forceinline__ void split2(float x, float& hf, float& lf){
  __hip_bfloat16 hb = __float2bfloat16(x);
  hf = __bfloat162float(hb);
  lf = x - hf;
}
__device__ __forceinline__ void pkhl(float x0, float x1, unsigned& hw_out, unsigned& lw_out){
  unsigned hw = cvtpk(x0, x1);
  float h0 = __uint_as_float(hw << 16);
  float h1 = __uint_as_float(hw & 0xffff0000u);
  lw_out = cvtpk(x0 - h0, x1 - h1);
  hw_out = hw;
}

// ======================= coeff kernel (U-group fragments) =======================
__global__ void coeff2_kernel(const float* __restrict__ wts, unsigned short* __restrict__ gfrag){
  const int g = blockIdx.x;          // 12
  const int tid = threadIdx.x;       // 128
  const int m = tid & 15, rp = tid >> 4;
  const int s = rp >> 1, reg = rp & 1;
  const int r0 = 4*s + 2*reg, r1 = r0 + 1;
  const int l = g/3, j0 = (g%3)*4;
  float ur0=1.f, ui0=0.f, ur1=1.f, ui1=0.f;
  #pragma unroll
  for(int i=0;i<4;++i){
    float o[8]; gate_coeffs(wts, l*NW + j0 + i, o);
    int mb=(m>>i)&1, rb0=(r0>>i)&1, rb1=(r1>>i)&1;
    float er=o[(mb*2+rb0)*2], ei=o[(mb*2+rb0)*2+1];
    float tr=ur0*er-ui0*ei, ti=ur0*ei+ui0*er; ur0=tr; ui0=ti;
    er=o[(mb*2+rb1)*2]; ei=o[(mb*2+rb1)*2+1];
    tr=ur1*er-ui1*ei; ti=ur1*ei+ui1*er; ur1=tr; ui1=ti;
  }
  float ur0h,ur0l,ur1h,ur1l, ui0h,ui0l,ui1h,ui1l;
  split2(ur0,ur0h,ur0l); split2(ur1,ur1h,ur1l);
  split2(ui0,ui0h,ui0l); split2(ui1,ui1h,ui1l);
  unsigned Urh=cvtpk(ur0h,ur1h), Url=cvtpk(ur0l,ur1l);
  unsigned Uih=cvtpk(ui0h,ui1h), Uil=cvtpk(ui0l,ui1l);
  unsigned nUih=Uih^0x80008000u, nUil=Uil^0x80008000u;
  const int lane = s*16 + m;
  unsigned p0[6]={Urh,Url,Uih,Uil,nUih,nUil};
  unsigned p1[6]={Url,Urh,Uil,Uih,nUil,nUih};
  #pragma unroll
  for(int f=0; f<6; ++f){
    unsigned* fp = (unsigned*)((char*)gfrag + ((size_t)((g*6+f)*64 + lane))*16);
    fp[reg] = p0[f];
    fp[2+reg] = p1[f];
  }
}

// ======================= MFMA main kernel (2 samples / block) =======================
#define LUT_BYTES (11*64*4)
__global__ __launch_bounds__(TPB,8)
void vqc_mfma(const float* __restrict__ inp, const unsigned short* __restrict__ gfrag,
              float* __restrict__ out){
  __shared__ __align__(16) char smem[2*DIM*8 + LUT_BYTES];
  __shared__ float cs2[2][NW], ss2[2][NW];
  __shared__ float red[8][NOUT];
  unsigned* blut = (unsigned*)(smem + 2*DIM*8);
  const int t = threadIdx.x, b = blockIdx.x, l = t&63;
  const int tt = t & 255, smp = t >> 8;
  char* ampc = smem + smp*(DIM*8);
  if(tt < NW){
    float x = inp[(b*2+smp)*NW+tt];
    float s,c; sincosf(0.78539816339744830962f*x,&s,&c);
    cs2[smp][tt]=c; ss2[smp][tt]=s;
  }
  // base-LUT fill: wbase/rbase nibble tables for exchanges g=1..11 (shared by both samples)
  for(int e=t; e<11*64; e+=TPB){
    int gg=(e>>6)+1, idx=e&63;
    int kind=idx>>4, nib=idx&15;
    unsigned v=0;
    #pragma unroll
    for(int j=0;j<4;++j){
      if((nib>>j)&1){
        int jj = j + ((kind&1)?4:0);
        v ^= (kind<2)? PL2.WBC[gg][jj] : PL2.RBC[gg][jj];
      }
    }
    blut[e]=v;
  }
  __syncthreads();
  float ctm[12], stm[12];
  #pragma unroll
  for(int p=0;p<12;++p){ ctm[p]=cs2[smp][11-p]; stm[p]=ss2[smp][11-p]; }
  unsigned sigb=0;
  #pragma unroll
  for(int j=0;j<8;++j) sigb ^= ((tt>>j)&1u)? PL2.SCOLt[j] : 0u;
  float pbase=1.f;
  #pragma unroll
  for(int p=0;p<12;++p)
    if(!((PL2C.TM>>p)&1u))
      pbase *= ((sigb>>p)&1u)? stm[p] : ctm[p];

  short8 AF[6];
  #pragma unroll
  for(int f=0; f<6; ++f)
    AF[f] = *(const short8*)((const char*)gfrag + ((size_t)(f*64 + l))*16);

  f32x4 Cr[4], Ci[4];
  #pragma unroll 1
  for(int g=0; g<12; ++g){
    unsigned rbase=0;
    if(g>0){
      const unsigned* bl = blut + (g-1)*64;
      unsigned wbase = bl[tt&15] ^ bl[16 + (tt>>4)];
      rbase          = bl[32 + (tt&15)] ^ bl[48 + (tt>>4)];
      __syncthreads();
      #pragma unroll
      for(int idx=0; idx<16; ++idx){
        const int T=idx>>2, q=idx&3;
        *(float2*)(ampc + (wbase ^ PL2.WOFF[g][idx])) = make_float2(Cr[T][q], Ci[T][q]);
      }
      __syncthreads();
    }
    #pragma unroll
    for(int T=0;T<4;++T){
      float2 v0,v1,v2,v3;
      if(g==0){
        float vv[4];
        #pragma unroll
        for(int rq=0;rq<4;++rq){
          unsigned sig = sigb ^ PL2.SK16[T*4+rq];
          float pk=pbase;
          #pragma unroll
          for(int p=0;p<12;++p)
            if((PL2C.TM>>p)&1u)
              pk *= ((sig>>p)&1u)? stm[p] : ctm[p];
          vv[rq]=pk;
        }
        v0=make_float2(vv[0],0.f); v1=make_float2(vv[1],0.f);
        v2=make_float2(vv[2],0.f); v3=make_float2(vv[3],0.f);
      } else {
        v0 = *(const float2*)(ampc + (rbase ^ PL2.ROFF[g][T*4+0]));
        v1 = *(const float2*)(ampc + (rbase ^ PL2.ROFF[g][T*4+1]));
        v2 = *(const float2*)(ampc + (rbase ^ PL2.ROFF[g][T*4+2]));
        v3 = *(const float2*)(ampc + (rbase ^ PL2.ROFF[g][T*4+3]));
      }
      unsigned h0,l0,h1,l1;
      pkhl(v0.x, v1.x, h0, l0);
      pkhl(v2.x, v3.x, h1, l1);
      u32x4 bu; bu.x=h0; bu.y=h1; bu.z=l0; bu.w=l1;
      short8 Br = __builtin_bit_cast(short8, bu);
      pkhl(v0.y, v1.y, h0, l0);
      pkhl(v2.y, v3.y, h1, l1);
      u32x4 cu; cu.x=h0; cu.y=h1; cu.z=l0; cu.w=l1;
      short8 Bi = __builtin_bit_cast(short8, cu);
      const f32x4 z = {0.f,0.f,0.f,0.f};
      f32x4 cr = __builtin_amdgcn_mfma_f32_16x16x32_bf16(AF[0], Br, z, 0,0,0);
      cr = __builtin_amdgcn_mfma_f32_16x16x32_bf16(AF[1], Br, cr, 0,0,0);
      cr = __builtin_amdgcn_mfma_f32_16x16x32_bf16(AF[4], Bi, cr, 0,0,0);
      cr = __builtin_amdgcn_mfma_f32_16x16x32_bf16(AF[5], Bi, cr, 0,0,0);
      f32x4 ci = __builtin_amdgcn_mfma_f32_16x16x32_bf16(AF[2], Br, z, 0,0,0);
      ci = __builtin_amdgcn_mfma_f32_16x16x32_bf16(AF[3], Br, ci, 0,0,0);
      ci = __builtin_amdgcn_mfma_f32_16x16x32_bf16(AF[0], Bi, ci, 0,0,0);
      ci = __builtin_amdgcn_mfma_f32_16x16x32_bf16(AF[1], Bi, ci, 0,0,0);
      Cr[T]=cr; Ci[T]=ci;
    }
    if(g<11){
      #pragma unroll
      for(int f=0; f<6; ++f)
        AF[f] = *(const short8*)((const char*)gfrag + ((size_t)(((g+1)*6+f)*64 + l))*16);
    }
  }
  float acc[NOUT]={0.f,0.f,0.f,0.f};
  float sg[NOUT];
  #pragma unroll
  for(int o=0;o<NOUT;++o)
    sg[o] = (__popc((unsigned)tt & PL2.SRt[o])&1)? -1.f : 1.f;
  #pragma unroll
  for(int idx=0; idx<16; ++idx){
    const int T=idx>>2, q=idx&3;
    float pr = Cr[T][q]*Cr[T][q] + Ci[T][q]*Ci[T][q];
    #pragma unroll
    for(int o=0;o<NOUT;++o){
      const bool kp = (PL2C.KP[o]>>idx)&1;
      float f = sg[o]*pr;
      acc[o] += kp? -f : f;
    }
  }
  #pragma unroll
  for(int o=0;o<NOUT;++o)
    #pragma unroll
    for(int off=32; off>0; off>>=1)
      acc[o] += __shfl_down(acc[o], off);
  __syncthreads();
  const int wv=t>>6, ln=t&63;
  if(ln==0){
    #pragma unroll
    for(int o=0;o<NOUT;++o) red[wv][o]=acc[o];
  }
  __syncthreads();
  if(tt<NOUT){
    const int w0 = smp*4;
    out[(b*2+smp)*NOUT+tt] = red[w0][tt]+red[w0+1][tt]+red[w0+2][tt]+red[w0+3][tt];
  }
}

// ======================= launch =======================
extern "C" void kernel_launch(void* const* d_in, const int* in_sizes, int n_in,
                              void* d_out, int out_size, void* d_ws, size_t ws_size,
                              hipStream_t stream) {
  const float* inp=(const float*)d_in[0];   // (1024,12) f32
  const float* wts=(const float*)d_in[1];   // (4,12,3) f32
  float* outp=(float*)d_out;                // (1024,4) f32
  const int B = in_sizes[0]/NW;
  unsigned short* gfrag=(unsigned short*)d_ws;   // 73728 B needed; ws is ample
  coeff2_kernel<<<12,128,0,stream>>>(wts,gfrag);
  vqc_mfma<<<B/2,TPB,0,stream>>>(inp,gfrag,outp);
}

// Round 13
// 39.680 us; speedup vs baseline: 1.0591x; 1.0591x over previous
//
#include <hip/hip_runtime.h>
#include <hip/hip_bf16.h>

#define NW 12
#define DIM 4096
#define NL 4
#define NGATE 48
#define NOUT 4
#define TPB 256

typedef float f32x2 __attribute__((ext_vector_type(2)));
typedef float f32x4 __attribute__((ext_vector_type(4)));
typedef unsigned u32x4 __attribute__((ext_vector_type(4)));
typedef short short8 __attribute__((ext_vector_type(8)));

// ======================= shared constexpr GF(2) machinery =======================
constexpr int pcnt(unsigned x){ return __builtin_popcount(x); }
constexpr int msbp(unsigned x){ return x ? 31-__builtin_clz(x) : -1; }
constexpr unsigned ring_fwd(unsigned x,int r){
  for(int w=0;w<NW;++w){ int c=NW-1-w,t=NW-1-((w+r)%NW); x^=((x>>c)&1u)<<t; } return x;
}
constexpr unsigned ring_rev(unsigned x,int r){
  for(int w=NW-1;w>=0;--w){ int c=NW-1-w,t=NW-1-((w+r)%NW); x^=((x>>c)&1u)<<t; } return x;
}
struct Mat { unsigned col[12]; };
constexpr unsigned apply_cols(const Mat&M, unsigned v){
  unsigned r=0; for(int j=0;j<12;++j) if((v>>j)&1u) r^=M.col[j]; return r;
}
constexpr unsigned apply_rows(const unsigned* rows, unsigned v){
  unsigned r=0; for(int i=0;i<12;++i) r|=(unsigned)(pcnt(rows[i]&v)&1)<<i; return r;
}
constexpr bool invert_rows(const Mat&M, unsigned* ri_out){
  unsigned rb[12]={}, ri[12]={};
  for(int i=0;i<12;++i){ unsigned r=0; for(int j=0;j<12;++j) r|=((M.col[j]>>i)&1u)<<j; rb[i]=r; ri[i]=1u<<i; }
  for(int c=0;c<12;++c){
    int piv=-1; for(int r=c;r<12;++r) if((rb[r]>>c)&1u){piv=r;break;}
    if(piv<0) return false;
    unsigned t=rb[c]; rb[c]=rb[piv]; rb[piv]=t; t=ri[c]; ri[c]=ri[piv]; ri[piv]=t;
    for(int r=0;r<12;++r) if(r!=c&&((rb[r]>>c)&1u)){ rb[r]^=rb[c]; ri[r]^=ri[c]; }
  }
  for(int i=0;i<12;++i) ri_out[i]=ri[i];
  return true;
}
constexpr int nullspace4(const unsigned* A0, unsigned* out){
  unsigned A[4]={}; for(int i=0;i<4;++i) A[i]=A0[i];
  int rank=0; int pivc[4]={-1,-1,-1,-1};
  for(int c=0;c<12&&rank<4;++c){
    int piv=-1; for(int r=rank;r<4;++r) if((A[r]>>c)&1u){piv=r;break;}
    if(piv<0) continue;
    unsigned t=A[rank];A[rank]=A[piv];A[piv]=t;
    for(int r=0;r<4;++r) if(r!=rank&&((A[r]>>c)&1u)) A[r]^=A[rank];
    pivc[rank]=c; ++rank;
  }
  if(rank!=4) return -1;
  bool ispiv[12]={};
  for(int r=0;r<4;++r) ispiv[pivc[r]]=true;
  int cnt=0;
  for(int f=0;f<12;++f) if(!ispiv[f]){
    unsigned v=1u<<f;
    for(int r=0;r<4;++r) if((A[r]>>f)&1u) v|=1u<<pivc[r];
    out[cnt++]=v;
  }
  return cnt;
}
struct Ech { unsigned r[12]; int lead[12]; int n; };
constexpr unsigned ech_red(const Ech&e, unsigned v){
  int mv=msbp(v);
  for(int i=0;i<e.n&&v;++i) if(e.lead[i]==mv){ v^=e.r[i]; mv=msbp(v); }
  return v;
}
constexpr void ech_add(Ech&e, unsigned v){
  int l=msbp(v); int pos=e.n;
  while(pos>0&&e.lead[pos-1]<l){ e.r[pos]=e.r[pos-1]; e.lead[pos]=e.lead[pos-1]; --pos; }
  e.r[pos]=v; e.lead[pos]=l; e.n+=1;
}

struct Circ {
  unsigned M[NL][12]; unsigned RM[NL][12]; unsigned MR[NOUT];
};
constexpr Circ make_circ(){
  Circ C{};
  unsigned cols[12]={}, icols[12]={};
  for(int p=0;p<12;++p){ cols[p]=1u<<p; icols[p]=1u<<p; }
  for(int l=0;l<NL;++l){
    for(int w=0;w<NW;++w){
      int p=NW-1-w;
      C.M[l][w]=icols[p];
      unsigned r=0; for(int j=0;j<12;++j) r|=((cols[j]>>p)&1u)<<j;
      C.RM[l][w]=r;
    }
    int rr=(l%(NW-1))+1;
    for(int j=0;j<12;++j) cols[j]=ring_fwd(cols[j],rr);
    unsigned nic[12]={};
    for(int p=0;p<12;++p){
      unsigned y=ring_rev(1u<<p,rr), v=0;
      for(int q=0;q<12;++q) if((y>>q)&1u) v^=icols[q];
      nic[p]=v;
    }
    for(int p=0;p<12;++p) icols[p]=nic[p];
  }
  for(int o=0;o<NOUT;++o){
    int p=NW-1-o; unsigned r=0;
    for(int j=0;j<12;++j) r|=((cols[j]>>p)&1u)<<j;
    C.MR[o]=r;
  }
  return C;
}

// ======================= Plan2: MFMA layout (R9-proven) =======================
constexpr unsigned amap(unsigned v){ return (v>>8)*2048u + (v&255u)*8u; }

struct Plan2 {
  unsigned SCOLt[8];
  unsigned SK16[16];
  unsigned TM;
  unsigned WBC[12][8], WOFF[12][16];
  unsigned RBC[12][8], ROFF[12][16];
  unsigned SRt[NOUT], KP[NOUT];
  bool ok;
};

constexpr Plan2 make_plan2(){
  Plan2 P{}; P.ok=true;
  constexpr Circ C = make_circ();
  const int SIGl[8] = {0,1,2,3,10,11,6,7};
  Mat Bprev{}; for(int j=0;j<12;++j) Bprev.col[j]=1u<<j;
  for(int g=0; g<12; ++g){
    int l=g/3, j0=(g%3)*4;
    unsigned mi[4]={}, rmi[4]={};
    for(int i=0;i<4;++i){ mi[i]=C.M[l][j0+i]; rmi[i]=C.RM[l][j0+i]; }
    unsigned u[8]={};
    if(nullspace4(rmi,u)!=8){ P.ok=false; return P; }
    unsigned binv[12]={};
    if(!invert_rows(Bprev,binv)){ P.ok=false; return P; }
    for(int s=0;s<8;++s) u[s]=apply_rows(binv,u[s]);
    Mat Bg{};
    for(int j=0;j<8;++j) Bg.col[j]=apply_cols(Bprev,u[j]);
    for(int i=0;i<4;++i) Bg.col[8+i]=mi[i];
    unsigned tinv[12]={};
    if(!invert_rows(Bg,tinv)){ P.ok=false; return P; }
    for(int i=0;i<4;++i)
      for(int j=0;j<12;++j){
        int want=(j==8+i)?1:0;
        if((pcnt(Bg.col[j]&rmi[i])&1)!=want){ P.ok=false; return P; }
      }
    if(g==0){
      for(int j=0;j<8;++j) P.SCOLt[j]=Bg.col[SIGl[j]];
      for(int idx=0;idx<16;++idx){
        unsigned v=0;
        if((idx>>2)&1) v^=Bg.col[4];
        if((idx>>2)&2) v^=Bg.col[5];
        if(idx&1) v^=Bg.col[8];
        if(idx&2) v^=Bg.col[9];
        P.SK16[idx]=v; P.TM|=v;
      }
    } else {
      unsigned rk[4]={};
      for(int i=0;i<4;++i){
        rk[i]=apply_rows(binv,mi[i]);
        if(apply_cols(Bprev,rk[i])!=mi[i]){ P.ok=false; return P; }
      }
      unsigned s2b[6]={u[0],u[1],u[2],u[3],rk[2],rk[3]};
      unsigned rows[12]={}; int nr=0;
      Ech P1{},P2{},ER{};
      for(int pick=0;pick<4;++pick){
        unsigned fx=0, fy=0;
        const int b1s[6]={0,1,2,3,10,11};
        for(int ii=0;ii<6;++ii){
          unsigned f=1u<<b1s[ii];
          unsigned p1=(f&15u)|(((f>>10)&3u)<<4);
          if(ech_red(P1,p1)){ fx=f; break; }
        }
        for(int bb=0;bb<12;++bb){
          unsigned f=1u<<bb, p2=0;
          for(int i2=0;i2<6;++i2) p2|=(unsigned)(pcnt(f&s2b[i2])&1)<<i2;
          if(ech_red(P2,p2)){ fy=f; break; }
        }
        if(!fx||!fy){ P.ok=false; return P; }
        unsigned cand[3]={fx,fy,fx^fy};
        unsigned chosen=0, cp1=0, cp2=0;
        for(int ci=0; ci<3 && !chosen; ++ci){
          unsigned f=cand[ci];
          unsigned p1=(f&15u)|(((f>>10)&3u)<<4);
          unsigned p2=0; for(int i2=0;i2<6;++i2) p2|=(unsigned)(pcnt(f&s2b[i2])&1)<<i2;
          if(ech_red(P1,p1)&&ech_red(P2,p2)){ chosen=f; cp1=p1; cp2=p2; }
        }
        if(!chosen){ P.ok=false; return P; }
        { unsigned v1=ech_red(P1,cp1); ech_add(P1,v1); }
        { unsigned v2=ech_red(P2,cp2); ech_add(P2,v2); }
        { unsigned vr=ech_red(ER,chosen); if(!vr){ P.ok=false; return P; } ech_add(ER,vr); }
        rows[nr++]=chosen;
      }
      for(int bb=0;bb<12 && nr<12;++bb){
        unsigned vr=ech_red(ER,1u<<bb); if(!vr) continue;
        ech_add(ER,vr); rows[nr++]=1u<<bb;
      }
      if(nr!=12){ P.ok=false; return P; }
      unsigned PhiCol[12]={};
      for(int j=0;j<12;++j){
        unsigned v=0;
        for(int i=0;i<12;++i) v|=(unsigned)((rows[i]>>j)&1u)<<i;
        PhiCol[j]=v;
      }
      unsigned PhiM[12]={};
      for(int j=0;j<12;++j){
        unsigned src=(j<8)? u[j] : rk[j-8];
        unsigned v=0;
        for(int q2=0;q2<12;++q2) if((src>>q2)&1u) v^=PhiCol[q2];
        PhiM[j]=v;
      }
      for(int j=0;j<8;++j){
        P.WBC[g][j]=amap(PhiCol[SIGl[j]]);
        P.RBC[g][j]=amap(PhiM[SIGl[j]]);
      }
      for(int idx=0;idx<16;++idx){
        unsigned wv=0, rv=0;
        if((idx>>2)&1){ wv^=PhiCol[4]; rv^=PhiM[4]; }
        if((idx>>2)&2){ wv^=PhiCol[5]; rv^=PhiM[5]; }
        if(idx&1){ wv^=PhiCol[8]; rv^=PhiM[8]; }
        if(idx&2){ wv^=PhiCol[9]; rv^=PhiM[9]; }
        P.WOFF[g][idx]=amap(wv); P.ROFF[g][idx]=amap(rv);
      }
    }
    Bprev=Bg;
  }
  for(int o=0;o<NOUT;++o){
    unsigned sr=0;
    for(int j=0;j<12;++j) sr|=(unsigned)(pcnt(Bprev.col[j]&C.MR[o])&1)<<j;
    unsigned srt=0;
    const int SIGl2[8] = {0,1,2,3,10,11,6,7};
    for(int j=0;j<8;++j) srt|=((sr>>SIGl2[j])&1u)<<j;
    P.SRt[o]=srt;
    unsigned kp=0;
    for(int idx=0;idx<16;++idx){
      int T=idx>>2, q=idx&3;
      unsigned bit=(((sr>>4)&1u)&(unsigned)(T&1))^(((sr>>5)&1u)&(unsigned)((T>>1)&1))
                  ^(((sr>>8)&1u)&(unsigned)(q&1))^(((sr>>9)&1u)&(unsigned)((q>>1)&1));
      kp|=bit<<idx;
    }
    P.KP[o]=kp;
  }
  return P;
}

constexpr Plan2 PL2C = make_plan2();
static_assert(PL2C.ok, "plan2 failed");
__device__ constexpr Plan2 PL2 = PL2C;

// ======================= device helpers =======================
__device__ __forceinline__ void gate_coeffs(const float* __restrict__ wts, int gi, float* o){
  const float* w = wts + gi*3;
  float st,ct;  sincosf(0.5f*w[1],&st,&ct);
  float sap,cap; sincosf(0.5f*(w[0]+w[2]),&sap,&cap);
  float sam,cam; sincosf(0.5f*(w[0]-w[2]),&sam,&cam);
  o[0]= cap*ct; o[1]=-sap*ct;
  o[2]=-cam*st; o[3]=-sam*st;
  o[4]= cam*st; o[5]=-sam*st;
  o[6]= cap*ct; o[7]= sap*ct;
}
__device__ __forceinline__ unsigned cvtpk(float a, float b){
  unsigned r; asm("v_cvt_pk_bf16_f32 %0, %1, %2" : "=v"(r) : "v"(a), "v"(b)); return r;
}
__device__ __forceinline__ void split2(float x, float& hf, float& lf){
  __hip_bfloat16 hb = __float2bfloat16(x);
  hf = __bfloat162float(hb);
  lf = x - hf;
}
__device__ __forceinline__ void pkhl(float x0, float x1, unsigned& hw_out, unsigned& lw_out){
  unsigned hw = cvtpk(x0, x1);
  float h0 = __uint_as_float(hw << 16);
  float h1 = __uint_as_float(hw & 0xffff0000u);
  lw_out = cvtpk(x0 - h0, x1 - h1);
  hw_out = hw;
}

// shared per-T compute: read 4 amps, convert, 8 MFMAs
__device__ __forceinline__ void do_mfma_T(const float2& v0, const float2& v1,
                                          const float2& v2, const float2& v3,
                                          const short8* AF, f32x4& cr_o, f32x4& ci_o){
  unsigned h0,l0,h1,l1;
  pkhl(v0.x, v1.x, h0, l0);
  pkhl(v2.x, v3.x, h1, l1);
  u32x4 bu; bu.x=h0; bu.y=h1; bu.z=l0; bu.w=l1;
  short8 Br = __builtin_bit_cast(short8, bu);
  pkhl(v0.y, v1.y, h0, l0);
  pkhl(v2.y, v3.y, h1, l1);
  u32x4 cu; cu.x=h0; cu.y=h1; cu.z=l0; cu.w=l1;
  short8 Bi = __builtin_bit_cast(short8, cu);
  const f32x4 z = {0.f,0.f,0.f,0.f};
  f32x4 cr = __builtin_amdgcn_mfma_f32_16x16x32_bf16(AF[0], Br, z, 0,0,0);
  cr = __builtin_amdgcn_mfma_f32_16x16x32_bf16(AF[1], Br, cr, 0,0,0);
  cr = __builtin_amdgcn_mfma_f32_16x16x32_bf16(AF[4], Bi, cr, 0,0,0);
  cr = __builtin_amdgcn_mfma_f32_16x16x32_bf16(AF[5], Bi, cr, 0,0,0);
  f32x4 ci = __builtin_amdgcn_mfma_f32_16x16x32_bf16(AF[2], Br, z, 0,0,0);
  ci = __builtin_amdgcn_mfma_f32_16x16x32_bf16(AF[3], Br, ci, 0,0,0);
  ci = __builtin_amdgcn_mfma_f32_16x16x32_bf16(AF[0], Bi, ci, 0,0,0);
  ci = __builtin_amdgcn_mfma_f32_16x16x32_bf16(AF[1], Bi, ci, 0,0,0);
  cr_o = cr; ci_o = ci;
}

// ======================= coeff kernel (U-group fragments) =======================
__global__ void coeff2_kernel(const float* __restrict__ wts, unsigned short* __restrict__ gfrag){
  const int g = blockIdx.x;          // 12
  const int tid = threadIdx.x;       // 128
  const int m = tid & 15, rp = tid >> 4;
  const int s = rp >> 1, reg = rp & 1;
  const int r0 = 4*s + 2*reg, r1 = r0 + 1;
  const int l = g/3, j0 = (g%3)*4;
  float ur0=1.f, ui0=0.f, ur1=1.f, ui1=0.f;
  #pragma unroll
  for(int i=0;i<4;++i){
    float o[8]; gate_coeffs(wts, l*NW + j0 + i, o);
    int mb=(m>>i)&1, rb0=(r0>>i)&1, rb1=(r1>>i)&1;
    float er=o[(mb*2+rb0)*2], ei=o[(mb*2+rb0)*2+1];
    float tr=ur0*er-ui0*ei, ti=ur0*ei+ui0*er; ur0=tr; ui0=ti;
    er=o[(mb*2+rb1)*2]; ei=o[(mb*2+rb1)*2+1];
    tr=ur1*er-ui1*ei; ti=ur1*ei+ui1*er; ur1=tr; ui1=ti;
  }
  float ur0h,ur0l,ur1h,ur1l, ui0h,ui0l,ui1h,ui1l;
  split2(ur0,ur0h,ur0l); split2(ur1,ur1h,ur1l);
  split2(ui0,ui0h,ui0l); split2(ui1,ui1h,ui1l);
  unsigned Urh=cvtpk(ur0h,ur1h), Url=cvtpk(ur0l,ur1l);
  unsigned Uih=cvtpk(ui0h,ui1h), Uil=cvtpk(ui0l,ui1l);
  unsigned nUih=Uih^0x80008000u, nUil=Uil^0x80008000u;
  const int lane = s*16 + m;
  unsigned p0[6]={Urh,Url,Uih,Uil,nUih,nUil};
  unsigned p1[6]={Url,Urh,Uil,Uih,nUil,nUih};
  #pragma unroll
  for(int f=0; f<6; ++f){
    unsigned* fp = (unsigned*)((char*)gfrag + ((size_t)((g*6+f)*64 + lane))*16);
    fp[reg] = p0[f];
    fp[2+reg] = p1[f];
  }
}

// ======================= MFMA main kernel =======================
// LUT: per exchange g-1 (11), 32 uint2 entries: [0..15]=(w_lo,r_lo) nibble lo,
// [16..31]=(w_hi,r_hi) nibble hi. One ds_read_b64 per half.
#define LUT_BYTES (11*32*8)
__global__ __launch_bounds__(TPB,4)
void vqc_mfma(const float* __restrict__ inp, const unsigned short* __restrict__ gfrag,
              float* __restrict__ out){
  __shared__ __align__(16) char smem[DIM*8 + LUT_BYTES];
  float* cs = (float*)smem; float* ss = cs+NW; float* red = cs+2*NW;
  char* ampc = smem;
  uint2* blut = (uint2*)(smem + DIM*8);
  const int t = threadIdx.x, b = blockIdx.x, l = t&63;
  if(t < NW){
    float x = inp[b*NW+t];
    float s,c; sincosf(0.78539816339744830962f*x,&s,&c);
    cs[t]=c; ss[t]=s;
  }
  // LUT fill
  for(int e=t; e<11*32; e+=TPB){
    int gg=(e>>5)+1, idx=e&31;
    int hi=idx>>4, nib=idx&15;
    unsigned wv=0, rv=0;
    #pragma unroll
    for(int j=0;j<4;++j){
      if((nib>>j)&1){
        int jj = j + (hi?4:0);
        wv ^= PL2.WBC[gg][jj];
        rv ^= PL2.RBC[gg][jj];
      }
    }
    blut[e]=make_uint2(wv,rv);
  }
  __syncthreads();
  float ctm[12], stm[12];
  #pragma unroll
  for(int p=0;p<12;++p){ ctm[p]=cs[11-p]; stm[p]=ss[11-p]; }
  unsigned sigb=0;
  #pragma unroll
  for(int j=0;j<8;++j) sigb ^= ((t>>j)&1u)? PL2.SCOLt[j] : 0u;
  float pbase=1.f;
  #pragma unroll
  for(int p=0;p<12;++p)
    if(!((PL2C.TM>>p)&1u))
      pbase *= ((sigb>>p)&1u)? stm[p] : ctm[p];

  short8 AF[6];
  #pragma unroll
  for(int f=0; f<6; ++f)
    AF[f] = *(const short8*)((const char*)gfrag + ((size_t)(f*64 + l))*16);

  f32x4 Cr[4], Ci[4];

  // ---- group 0 (peeled): amps generated in-register ----
  {
    #pragma unroll
    for(int T=0;T<4;++T){
      float vv[4];
      #pragma unroll
      for(int rq=0;rq<4;++rq){
        unsigned sig = sigb ^ PL2.SK16[T*4+rq];
        float pk=pbase;
        #pragma unroll
        for(int p=0;p<12;++p)
          if((PL2C.TM>>p)&1u)
            pk *= ((sig>>p)&1u)? stm[p] : ctm[p];
        vv[rq]=pk;
      }
      float2 v0=make_float2(vv[0],0.f), v1=make_float2(vv[1],0.f);
      float2 v2=make_float2(vv[2],0.f), v3=make_float2(vv[3],0.f);
      __builtin_amdgcn_s_setprio(1);
      do_mfma_T(v0,v1,v2,v3, AF, Cr[T], Ci[T]);
      __builtin_amdgcn_s_setprio(0);
    }
    #pragma unroll
    for(int f=0; f<6; ++f)
      AF[f] = *(const short8*)((const char*)gfrag + ((size_t)((6+f)*64 + l))*16);
  }

  // ---- groups 1..11 (branch-free) ----
  #pragma unroll 1
  for(int g=1; g<12; ++g){
    const uint2* bl = blut + (g-1)*32;
    uint2 lo = bl[t&15];
    uint2 hi = bl[16 + (t>>4)];
    unsigned wbase = lo.x ^ hi.x;
    unsigned rbase = lo.y ^ hi.y;
    __syncthreads();
    #pragma unroll
    for(int idx=0; idx<16; ++idx){
      const int T=idx>>2, q=idx&3;
      *(float2*)(ampc + (wbase ^ PL2.WOFF[g][idx])) = make_float2(Cr[T][q], Ci[T][q]);
    }
    __syncthreads();
    #pragma unroll
    for(int T=0;T<4;++T){
      float2 v0 = *(const float2*)(ampc + (rbase ^ PL2.ROFF[g][T*4+0]));
      float2 v1 = *(const float2*)(ampc + (rbase ^ PL2.ROFF[g][T*4+1]));
      float2 v2 = *(const float2*)(ampc + (rbase ^ PL2.ROFF[g][T*4+2]));
      float2 v3 = *(const float2*)(ampc + (rbase ^ PL2.ROFF[g][T*4+3]));
      __builtin_amdgcn_s_setprio(1);
      do_mfma_T(v0,v1,v2,v3, AF, Cr[T], Ci[T]);
      __builtin_amdgcn_s_setprio(0);
    }
    if(g<11){
      #pragma unroll
      for(int f=0; f<6; ++f)
        AF[f] = *(const short8*)((const char*)gfrag + ((size_t)(((g+1)*6+f)*64 + l))*16);
    }
  }

  float acc[NOUT]={0.f,0.f,0.f,0.f};
  float sg[NOUT];
  #pragma unroll
  for(int o=0;o<NOUT;++o)
    sg[o] = (__popc((unsigned)t & PL2.SRt[o])&1)? -1.f : 1.f;
  #pragma unroll
  for(int idx=0; idx<16; ++idx){
    const int T=idx>>2, q=idx&3;
    float pr = Cr[T][q]*Cr[T][q] + Ci[T][q]*Ci[T][q];
    #pragma unroll
    for(int o=0;o<NOUT;++o){
      const bool kp = (PL2C.KP[o]>>idx)&1;
      float f = sg[o]*pr;
      acc[o] += kp? -f : f;
    }
  }
  #pragma unroll
  for(int o=0;o<NOUT;++o)
    #pragma unroll
    for(int off=32; off>0; off>>=1)
      acc[o] += __shfl_down(acc[o], off);
  __syncthreads();
  const int wv=t>>6, ln=t&63;
  if(ln==0){
    #pragma unroll
    for(int o=0;o<NOUT;++o) red[wv*NOUT+o]=acc[o];
  }
  __syncthreads();
  if(t<NOUT)
    out[b*NOUT+t] = red[0*NOUT+t]+red[1*NOUT+t]+red[2*NOUT+t]+red[3*NOUT+t];
}

// ======================= launch =======================
extern "C" void kernel_launch(void* const* d_in, const int* in_sizes, int n_in,
                              void* d_out, int out_size, void* d_ws, size_t ws_size,
                              hipStream_t stream) {
  const float* inp=(const float*)d_in[0];   // (1024,12) f32
  const float* wts=(const float*)d_in[1];   // (4,12,3) f32
  float* outp=(float*)d_out;                // (1024,4) f32
  const int B = in_sizes[0]/NW;
  unsigned short* gfrag=(unsigned short*)d_ws;   // 73728 B needed; ws is ample
  coeff2_kernel<<<12,128,0,stream>>>(wts,gfrag);
  vqc_mfma<<<B,TPB,0,stream>>>(inp,gfrag,outp);
}